// Round 20
// baseline (131.604 us; speedup 1.0000x reference)
//
#include <hip/hip_runtime.h>
#include <hip/hip_bf16.h>

// Joiner: logits[n,t,u,v] = sum_d tanh(enc[n,t,d]+dec[n,u,d]) * W[v,d] + b[v]
// N=8 T=200 U=100 D=512 V=500  -> GEMM M=160000, K=512, N=500 (padded 512)
//
// R17 = R16 (131us) with the K-step body split into 4 INTERLEAVED SUB-PHASES
// (m196/T3 fine-interleave): each sub-phase issues {2 next-B loads, 1
// ds_read of the NEXT A-fragment, 2 tanh cvt_pk pairs} then runs 8 MFMAs on
// the PREVIOUS A-fragment -- every MFMA cluster covers the adjacent ds_read
// latency, loads spread across the step instead of bunching at the top.
// a0 carries the first fragment across the raw barrier. Everything else =
// R16: BM=64 BN=512 256thr, T4 counted-vmcnt B reg-dbuf across raw lgkm-only
// barriers, tanh-staged dbuf-LDS A, streamed 16-row LDS epilogue.

#define NB 8
#define TT 200
#define UU 100
#define DD 512
#define VV 500
#define VP 512
#define BM 64
#define BK 32
#define KSTEPS 16          // 512/32
#define THREADS 256
#define LDA 40             // BK + 8 pad (ushort units, 80B row stride)
#define MROWS (NB*TT*UU)   // 160000
#define MBLOCKS (MROWS/BM) // 2500

typedef __attribute__((ext_vector_type(4))) float         f32x4;
typedef __attribute__((ext_vector_type(8))) short         s16x8;
typedef __attribute__((ext_vector_type(4))) unsigned int  u32x4;

#define RAW_BAR() do { asm volatile("s_waitcnt lgkmcnt(0)" ::: "memory"); \
                       __builtin_amdgcn_s_barrier(); } while (0)

__device__ __forceinline__ unsigned short f2bf(float f) {
    unsigned int u = __builtin_bit_cast(unsigned int, f);
    u = (u + 0x7FFFu + ((u >> 16) & 1u)) >> 16;   // round-to-nearest-even
    return (unsigned short)u;
}

// pack 2 f32 -> 2 bf16 (RNE) in one instruction
__device__ __forceinline__ unsigned int cvt_pk_bf16(float a, float b) {
    unsigned int r;
    asm("v_cvt_pk_bf16_f32 %0, %1, %2" : "=v"(r) : "v"(a), "v"(b));
    return r;
}

__device__ __forceinline__ float fast_tanh(float x) {
    // tanh(x) = 1 - 2/(1+2^(2x*log2e)); saturations via exp inf/0
    float e = __builtin_amdgcn_exp2f(x * 2.88539008177793f);
    return __builtin_fmaf(-2.0f, __builtin_amdgcn_rcpf(e + 1.0f), 1.0f);
}

// ---- prep: W (500x512 f32) -> bf16, padded to 512 rows, tiled [kc][v][32] ----
__global__ void prep_w(const float* __restrict__ W, unsigned short* __restrict__ Wt) {
    int idx = blockIdx.x * 256 + threadIdx.x;   // 0 .. 512*512-1
    int k = idx & 511;
    int v = idx >> 9;
    float val = (v < VV) ? W[v * DD + k] : 0.0f;
    Wt[(k >> 5) * (VP * BK) + v * BK + (k & 31)] = f2bf(val);
}

// One K-step, 4 interleaved sub-phases. At entry: a0 holds A[kc] frag m=0,
// BC holds B[kc] (in flight, counted vmcnt), e/d hold enc/dec[kc+1].
// At exit (kc<15): a0 holds A[kc+1] frag m=0 from NXT.
#define KBODY(kc, CUR, NXT, BC, BNX)                                          \
  {                                                                           \
    s16x8 aF1, aF2, aF3;                                                      \
    u32x4 wds;                                                                \
    f32x4 ne0, ne1, nd0, nd1;                                                 \
    /* ---- sub-phase 0: MFMA m=0 on a0 ---- */                               \
    if ((kc) < KSTEPS - 1) {                                                  \
      BNX[0] = *(const s16x8*)(wptr + ((kc)+1) * (VP * BK) + 0 * (16*BK));    \
      BNX[1] = *(const s16x8*)(wptr + ((kc)+1) * (VP * BK) + 1 * (16*BK));    \
    }                                                                         \
    if ((kc) < KSTEPS - 2) {                                                  \
      const float* e2 = ep + ((kc)+2) * BK;                                   \
      ne0 = *(const f32x4*)(e2);  ne1 = *(const f32x4*)(e2 + 4);              \
    }                                                                         \
    aF1 = *(const s16x8*)(&CUR[(1 * 16 + lr) * LDA + lk * 8]);                \
    wds[0] = cvt_pk_bf16(fast_tanh(e0[0]+d0[0]), fast_tanh(e0[1]+d0[1]));     \
    wds[1] = cvt_pk_bf16(fast_tanh(e0[2]+d0[2]), fast_tanh(e0[3]+d0[3]));     \
    __builtin_amdgcn_s_setprio(1);                                            \
    _Pragma("unroll")                                                         \
    for (int f = 0; f < 8; ++f)                                               \
      acc[0][f] = __builtin_amdgcn_mfma_f32_16x16x32_bf16(a0, BC[f],          \
                                                          acc[0][f],0,0,0);   \
    __builtin_amdgcn_s_setprio(0);                                            \
    /* ---- sub-phase 1: MFMA m=1 on aF1 ---- */                              \
    if ((kc) < KSTEPS - 1) {                                                  \
      BNX[2] = *(const s16x8*)(wptr + ((kc)+1) * (VP * BK) + 2 * (16*BK));    \
      BNX[3] = *(const s16x8*)(wptr + ((kc)+1) * (VP * BK) + 3 * (16*BK));    \
    }                                                                         \
    if ((kc) < KSTEPS - 2) {                                                  \
      const float* d2 = dp + ((kc)+2) * BK;                                   \
      nd0 = *(const f32x4*)(d2);  nd1 = *(const f32x4*)(d2 + 4);              \
    }                                                                         \
    aF2 = *(const s16x8*)(&CUR[(2 * 16 + lr) * LDA + lk * 8]);                \
    wds[2] = cvt_pk_bf16(fast_tanh(e1[0]+d1[0]), fast_tanh(e1[1]+d1[1]));     \
    wds[3] = cvt_pk_bf16(fast_tanh(e1[2]+d1[2]), fast_tanh(e1[3]+d1[3]));     \
    __builtin_amdgcn_s_setprio(1);                                            \
    _Pragma("unroll")                                                         \
    for (int f = 0; f < 8; ++f)                                               \
      acc[1][f] = __builtin_amdgcn_mfma_f32_16x16x32_bf16(aF1, BC[f],         \
                                                          acc[1][f],0,0,0);   \
    __builtin_amdgcn_s_setprio(0);                                            \
    /* ---- sub-phase 2: MFMA m=2 on aF2 ---- */                              \
    if ((kc) < KSTEPS - 1) {                                                  \
      BNX[4] = *(const s16x8*)(wptr + ((kc)+1) * (VP * BK) + 4 * (16*BK));    \
      BNX[5] = *(const s16x8*)(wptr + ((kc)+1) * (VP * BK) + 5 * (16*BK));    \
      *(u32x4*)(&NXT[srow * LDA + sk]) = wds;                                 \
    }                                                                         \
    aF3 = *(const s16x8*)(&CUR[(3 * 16 + lr) * LDA + lk * 8]);                \
    __builtin_amdgcn_s_setprio(1);                                            \
    _Pragma("unroll")                                                         \
    for (int f = 0; f < 8; ++f)                                               \
      acc[2][f] = __builtin_amdgcn_mfma_f32_16x16x32_bf16(aF2, BC[f],         \
                                                          acc[2][f],0,0,0);   \
    __builtin_amdgcn_s_setprio(0);                                            \
    /* ---- sub-phase 3: MFMA m=3 on aF3 ---- */                              \
    if ((kc) < KSTEPS - 1) {                                                  \
      BNX[6] = *(const s16x8*)(wptr + ((kc)+1) * (VP * BK) + 6 * (16*BK));    \
      BNX[7] = *(const s16x8*)(wptr + ((kc)+1) * (VP * BK) + 7 * (16*BK));    \
    }                                                                         \
    if ((kc) < KSTEPS - 2) {                                                  \
      e0 = ne0; e1 = ne1; d0 = nd0; d1 = nd1;                                 \
    }                                                                         \
    __builtin_amdgcn_s_setprio(1);                                            \
    _Pragma("unroll")                                                         \
    for (int f = 0; f < 8; ++f)                                               \
      acc[3][f] = __builtin_amdgcn_mfma_f32_16x16x32_bf16(aF3, BC[f],         \
                                                          acc[3][f],0,0,0);   \
    __builtin_amdgcn_s_setprio(0);                                            \
    /* raw barrier (LDS only); reload a0 from the next buffer */              \
    if ((kc) < KSTEPS - 1) {                                                  \
      RAW_BAR();                                                              \
      a0 = *(const s16x8*)(&NXT[(0 * 16 + lr) * LDA + lk * 8]);               \
    }                                                                         \
  }

__global__ __launch_bounds__(THREADS, 2) void joiner_kernel(
    const float* __restrict__ enc, const float* __restrict__ dec,
    const unsigned short* __restrict__ Wt, const float* __restrict__ bias,
    float* __restrict__ out)
{
    // union: K-loop A dbuf (2 x 5120 B) / epilogue chunk 16x500 f32 (32000 B)
    __shared__ __align__(16) char smem[32000];
    unsigned short* lA0 = (unsigned short*)smem;
    unsigned short* lA1 = (unsigned short*)(smem + BM * LDA * 2);

    const int tid  = threadIdx.x;
    const int mb   = blockIdx.x;
    const int lane = tid & 63;
    const int wn   = tid >> 6;       // 0..3: 128-col quarter
    const int lr   = lane & 15;
    const int lk   = lane >> 4;

    // staging: each thread produces 8 activations of one row
    const int srow = tid >> 2;          // 0..63
    const int sk   = (tid & 3) << 3;    // 0,8,16,24

    int r   = mb * BM + srow;
    int n   = r / (TT * UU);
    int rem = r - n * (TT * UU);
    int t   = rem / UU;
    int u   = rem - t * UU;
    const float* ep = enc + (n * TT + t) * DD + sk;
    const float* dp = dec + (n * UU + u) * DD + sk;

    // per-thread B pointer into pre-tiled Wt: v = wn*128 + f*16 + lr, k = lk*8
    const unsigned short* wptr = Wt + (wn * 128 + lr) * BK + lk * 8;

    f32x4 e0, e1, d0, d1;
    s16x8 b0[8], b1[8];
    s16x8 a0;

    // ---- prologue: e/d[0], issue B[0], stage A[0], e/d[1], raw barrier ----
    e0 = *(const f32x4*)(ep);     e1 = *(const f32x4*)(ep + 4);
    d0 = *(const f32x4*)(dp);     d1 = *(const f32x4*)(dp + 4);
    #pragma unroll
    for (int f = 0; f < 8; ++f)
        b0[f] = *(const s16x8*)(wptr + f * (16 * BK));
    {
        u32x4 wds;
        wds[0] = cvt_pk_bf16(fast_tanh(e0[0]+d0[0]), fast_tanh(e0[1]+d0[1]));
        wds[1] = cvt_pk_bf16(fast_tanh(e0[2]+d0[2]), fast_tanh(e0[3]+d0[3]));
        wds[2] = cvt_pk_bf16(fast_tanh(e1[0]+d1[0]), fast_tanh(e1[1]+d1[1]));
        wds[3] = cvt_pk_bf16(fast_tanh(e1[2]+d1[2]), fast_tanh(e1[3]+d1[3]));
        *(u32x4*)(&lA0[srow * LDA + sk]) = wds;
    }
    e0 = *(const f32x4*)(ep + BK);     e1 = *(const f32x4*)(ep + BK + 4);
    d0 = *(const f32x4*)(dp + BK);     d1 = *(const f32x4*)(dp + BK + 4);
    RAW_BAR();
    a0 = *(const s16x8*)(&lA0[(0 * 16 + lr) * LDA + lk * 8]);

    f32x4 acc[4][8];
    #pragma unroll
    for (int m = 0; m < 4; ++m)
        #pragma unroll
        for (int f = 0; f < 8; ++f)
            acc[m][f] = (f32x4){0.f, 0.f, 0.f, 0.f};

    // ---- K-loop: 8 x 2 bodies; B reg-dbuf b0/b1, A LDS-dbuf lA0/lA1 ----
    #pragma unroll
    for (int kk = 0; kk < KSTEPS; kk += 2) {
        KBODY(kk,     lA0, lA1, b0, b1)
        KBODY(kk + 1, lA1, lA0, b1, b0)
    }

    // ---- epilogue: acc -> LDS 16-row chunks -> streaming f32x4 stores ----
    float bv[8];
    #pragma unroll
    for (int f = 0; f < 8; ++f) {
        int v = wn * 128 + f * 16 + lr;
        bv[f] = (v < VV) ? bias[v] : 0.0f;
    }

    float* lchunk = (float*)smem;                 // 16*500 f32 = 32000 B
    float* outbase = out + (long)mb * BM * VV;

    for (int m = 0; m < 4; ++m) {
        RAW_BAR();   // K-loop LDS reads done / previous chunk streamed
        #pragma unroll
        for (int f = 0; f < 8; ++f) {
            int v = wn * 128 + f * 16 + lr;
            if (v < VV) {
                #pragma unroll
                for (int q = 0; q < 4; ++q)
                    lchunk[(lk * 4 + q) * VV + v] = acc[m][f][q] + bv[f];
            }
        }
        RAW_BAR();   // chunk writes visible
        // 16 rows x 500 f32 = 8000 contiguous floats = 2000 f32x4
        float* dst = outbase + m * 16 * VV;
        #pragma unroll
        for (int i = 0; i < 8; ++i) {
            int c = i * THREADS + tid;
            if (c < 2000)
                *(f32x4*)(dst + c * 4) = *(const f32x4*)(lchunk + c * 4);
        }
    }
}

extern "C" void kernel_launch(void* const* d_in, const int* in_sizes, int n_in,
                              void* d_out, int out_size, void* d_ws, size_t ws_size,
                              hipStream_t stream) {
    const float* enc = (const float*)d_in[0];
    const float* dec = (const float*)d_in[1];
    const float* W   = (const float*)d_in[2];
    const float* b   = (const float*)d_in[3];
    float* out = (float*)d_out;
    unsigned short* Wt = (unsigned short*)d_ws;   // 512*512*2 = 512 KB

    prep_w<<<dim3((VP * DD) / 256), dim3(256), 0, stream>>>(W, Wt);
    joiner_kernel<<<dim3(MBLOCKS), dim3(THREADS), 0, stream>>>(enc, dec, Wt, b, out);
}